// Round 1
// baseline (1052.951 us; speedup 1.0000x reference)
//
#include <hip/hip_runtime.h>
#include <hip/hip_bf16.h>
#include <stdint.h>

#define MAX_NORM_F 0.99999f
#define EPS_F 1e-7f
#define VOCAB 50257
#define VPAD 50304
#define NTOK 4096
#define DIM 256

typedef __attribute__((ext_vector_type(4))) float f32x4;
typedef __attribute__((ext_vector_type(8))) unsigned short u16x8;

typedef const __attribute__((address_space(1))) void gvoid_t;
typedef __attribute__((address_space(3))) void svoid_t;
#define GLDS16(g, l) \
  __builtin_amdgcn_global_load_lds((gvoid_t*)(g), (svoid_t*)(l), 16, 0, 0)

__device__ __forceinline__ unsigned short f2bf(float x) {
  union { float f; uint32_t u; } c; c.f = x;
  uint32_t r = c.u + 0x7FFFu + ((c.u >> 16) & 1u);
  return (unsigned short)(r >> 16);
}

// One wave per row: proj onto Poincare ball, cast to bf16, write ||x||^2 (post-proj).
__global__ __launch_bounds__(256) void proj_cast_kernel(
    const float* __restrict__ src, unsigned short* __restrict__ dst,
    float* __restrict__ n2, int nrows)
{
  const int lane = threadIdx.x & 63;
  const int row  = blockIdx.x * 4 + (threadIdx.x >> 6);
  if (row >= nrows) return;
  const float4 v = *reinterpret_cast<const float4*>(src + (size_t)row * DIM + lane * 4);
  float s = v.x * v.x + v.y * v.y + v.z * v.z + v.w * v.w;
  #pragma unroll
  for (int off = 32; off > 0; off >>= 1) s += __shfl_xor(s, off);
  const float norm  = sqrtf(s);
  const float scale = (norm > MAX_NORM_F) ? (MAX_NORM_F / fmaxf(norm, EPS_F)) : 1.0f;
  ushort4 o;
  o.x = f2bf(v.x * scale);
  o.y = f2bf(v.y * scale);
  o.z = f2bf(v.z * scale);
  o.w = f2bf(v.w * scale);
  *reinterpret_cast<ushort4*>(dst + (size_t)row * DIM + lane * 4) = o;
  if (lane == 0) n2[row] = s * scale * scale;
}

// 128x128 tile, BK=32, 4 waves (2x2), mfma_f32_16x16x32_bf16, double-buffered LDS,
// global_load_lds staging with row-XOR swizzle (inverse swizzle folded into the
// per-lane global source address; LDS destination stays linear).
__global__ __launch_bounds__(256) void hyp_head_kernel(
    const unsigned short* __restrict__ hb,   // [4096][256] bf16 (proj'd)
    const unsigned short* __restrict__ vb,   // [50304][256] bf16 (proj'd, padded)
    const float* __restrict__ h2a,           // [4096]
    const float* __restrict__ v2a,           // [50304]
    float* __restrict__ out)                 // [4096][50257]
{
  __shared__ __attribute__((aligned(1024))) char smem[2][16384]; // per buf: A 8KB | B 8KB

  const int tid  = threadIdx.x;
  const int w    = tid >> 6;
  const int lane = tid & 63;
  const int mt   = blockIdx.x & 31;
  const int nt   = blockIdx.x >> 5;
  const int row0 = mt << 7;
  const int col0 = nt << 7;
  const int wm   = w >> 1, wn = w & 1;    // wave computes 64x64
  const int l15  = lane & 15;
  const int l4   = lane >> 4;

  // ---- staging address setup ----
  // LDS linear pos for lane l, call c: p = w*2048 + c*1024 + l*16
  //   local row r = p/64 = w*32 + c*16 + (l>>2);  slot = (p/16)&3 = l&3
  // swizzle: LDS slot s holds global k-chunk (s ^ ((r>>1)&3)).
  // (r>>1)&3 is invariant under r += 16, so chunk is constant across calls.
  const int srow0 = (w << 5) + (lane >> 2);
  const int chunk = ((lane & 3) ^ (srow0 >> 1)) & 3;
  const size_t gAoff = (size_t)(row0 + srow0) * 512 + chunk * 16; // 512 B per row
  const size_t gBoff = (size_t)(col0 + srow0) * 512 + chunk * 16;

  // ---- fragment read offsets (swizzled) ----
  int offA[4], offB[4];
  #pragma unroll
  for (int f = 0; f < 4; ++f) {
    const int rA = (wm << 6) + (f << 4) + l15;
    offA[f] = (rA << 6) + (((l4 ^ (rA >> 1)) & 3) << 4);
    const int rB = (wn << 6) + (f << 4) + l15;
    offB[f] = (rB << 6) + (((l4 ^ (rB >> 1)) & 3) << 4);
  }

  f32x4 acc[4][4];
  #pragma unroll
  for (int i = 0; i < 4; ++i)
    #pragma unroll
    for (int j = 0; j < 4; ++j)
      acc[i][j] = (f32x4){0.f, 0.f, 0.f, 0.f};

  const char* gA = (const char*)hb + gAoff;
  const char* gB = (const char*)vb + gBoff;

  auto stage = [&](int kt, int b) {
    const char* a0 = gA + (size_t)kt * 64;   // 32 bf16 = 64 B per K-tile per row
    const char* b0 = gB + (size_t)kt * 64;
    char* la = &smem[b][(w << 11)];
    char* lb = &smem[b][8192 + (w << 11)];
    GLDS16(a0,        la);
    GLDS16(a0 + 8192, la + 1024);   // +16 rows = +16*512 B global
    GLDS16(b0,        lb);
    GLDS16(b0 + 8192, lb + 1024);
  };

  stage(0, 0);
  __syncthreads();

  #pragma unroll
  for (int kt = 0; kt < 8; ++kt) {
    const int b = kt & 1;
    if (kt < 7) stage(kt + 1, b ^ 1);
    const char* sA = &smem[b][0];
    const char* sB = &smem[b][8192];
    u16x8 af[4], bfr[4];
    #pragma unroll
    for (int f = 0; f < 4; ++f) {
      af[f]  = *reinterpret_cast<const u16x8*>(sA + offA[f]);
      bfr[f] = *reinterpret_cast<const u16x8*>(sB + offB[f]);
    }
    #pragma unroll
    for (int i = 0; i < 4; ++i)
      #pragma unroll
      for (int j = 0; j < 4; ++j)
        asm volatile("v_mfma_f32_16x16x32_bf16 %0, %1, %2, %0"
                     : "+v"(acc[i][j])
                     : "v"(af[i]), "v"(bfr[j]));
    __syncthreads();
  }

  // ---- fused epilogue: poincare distance ----
  const int rbase = row0 + (wm << 6) + (l4 << 2);
  const int cbase = col0 + (wn << 6) + l15;

  float hv[4][4], om[4][4], vv[4], ovm[4];
  #pragma unroll
  for (int i = 0; i < 4; ++i)
    #pragma unroll
    for (int r = 0; r < 4; ++r) {
      const float t = h2a[rbase + (i << 4) + r];
      hv[i][r] = t; om[i][r] = 1.0f - t;
    }
  #pragma unroll
  for (int j = 0; j < 4; ++j) {
    const float t = v2a[cbase + (j << 4)];
    vv[j] = t; ovm[j] = 1.0f - t;
  }

  #pragma unroll
  for (int i = 0; i < 4; ++i) {
    #pragma unroll
    for (int r = 0; r < 4; ++r) {
      float* orow = out + (size_t)(rbase + (i << 4) + r) * VOCAB;
      const float a2 = hv[i][r], oma = om[i][r];
      #pragma unroll
      for (int j = 0; j < 4; ++j) {
        const int gcol = cbase + (j << 4);
        const float dot = acc[i][j][r];
        float sq  = fmaxf(a2 + vv[j] - 2.0f * dot, 0.0f);
        float den = fmaxf(oma * ovm[j], EPS_F);
        float arg = fmaxf(1.0f + 2.0f * sq / den, 1.0f + 1e-7f);
        float dst = __log2f(arg + sqrtf(arg * arg - 1.0f)) * 0.6931471805599453f;
        if (gcol < VOCAB) orow[gcol] = -dst;
      }
    }
  }
}

extern "C" void kernel_launch(void* const* d_in, const int* in_sizes, int n_in,
                              void* d_out, int out_size, void* d_ws, size_t ws_size,
                              hipStream_t stream) {
  const float* h = (const float*)d_in[0];  // [4,1024,256]
  const float* v = (const float*)d_in[1];  // [50257,256]
  float* out = (float*)d_out;              // [4096][50257]
  char* ws = (char*)d_ws;

  unsigned short* hb = (unsigned short*)ws;                         // 2,097,152 B
  unsigned short* vb = (unsigned short*)(ws + 2097152);             // 25,755,648 B
  float* h2 = (float*)(ws + 2097152 + 25755648);                    // 16,384 B
  float* v2 = (float*)(ws + 2097152 + 25755648 + 16384);            // 201,216 B

  proj_cast_kernel<<<NTOK / 4, 256, 0, stream>>>(h, hb, h2, NTOK);
  proj_cast_kernel<<<(VOCAB + 3) / 4, 256, 0, stream>>>(v, vb, v2, VOCAB);
  hyp_head_kernel<<<32 * (VPAD / 128), 256, 0, stream>>>(hb, vb, h2, v2, out);
}